// Round 7
// baseline (291.503 us; speedup 1.0000x reference)
//
#include <hip/hip_runtime.h>

#define SEQn   512
#define BATCHn 4096
#define INn    9
#define HIDn   64
#define OUTn   10
#define LAG    33          // h2 chain lag behind h1 (prefetch-safety: see block-wait proof)
#define ROW1   72          // u16 elems per h-ring row (144 B)
#define U2P    72          // f32 elems per u2 ring row (288 B)

typedef __attribute__((ext_vector_type(4))) float    f32x4;
typedef __attribute__((ext_vector_type(4))) _Float16 f16x4;
typedef _Float16 half2_t __attribute__((ext_vector_type(2)));
typedef unsigned short u16;
typedef unsigned int   u32;

#define MFMA16(A,B,C) __builtin_amdgcn_mfma_f32_16x16x16f16((A),(B),(C),0,0,0)

#if __has_builtin(__builtin_amdgcn_fdot2)
#define DOT2(a,b,c) __builtin_amdgcn_fdot2((a),(b),(c),false)
#else
__device__ __forceinline__ float DOT2(half2_t a, half2_t b, float c){
    return __builtin_fmaf((float)a.x,(float)b.x, __builtin_fmaf((float)a.y,(float)b.y,c));
}
#endif
#define H2(u) __builtin_bit_cast(half2_t, (u))

// tanh(y) given x = 2*log2(e)*y  (2*log2e pre-folded into weights/biases)
__device__ __forceinline__ float tanh_pre(float x){
    float e = __builtin_amdgcn_exp2f(x);
    float r = __builtin_amdgcn_rcpf(e + 1.0f);
    return __builtin_fmaf(-2.0f, r, 1.0f);
}
__device__ __forceinline__ u16 f2h(float v){ return __builtin_bit_cast(u16, (_Float16)v); }
__device__ __forceinline__ f16x4 cvt4(f32x4 a){
    f16x4 r = {(_Float16)a.x, (_Float16)a.y, (_Float16)a.z, (_Float16)a.w};
    return r;
}

// lane-owned weight row scaled by s: 64 f32 -> 32 half2 regs (for DOT2 matvec)
__device__ __forceinline__ void load_w16s(const float* __restrict__ W, int row, float s, half2_t* wr){
#pragma unroll
    for (int c = 0; c < 16; ++c){
        f32x4 v = *(const f32x4*)&W[row*HIDn + c*4];
        wr[2*c]   = half2_t{(_Float16)(v.x*s), (_Float16)(v.y*s)};
        wr[2*c+1] = half2_t{(_Float16)(v.z*s), (_Float16)(v.w*s)};
    }
}

// 64-dot, 8 accumulators x 4-deep chains
__device__ __forceinline__ float dot64r8(const uint4* v, const half2_t* wr, float acc){
    float s0=acc, s1=0.f, s2=0.f, s3=0.f, s4=0.f, s5=0.f, s6=0.f, s7=0.f;
#pragma unroll
    for (int q = 0; q < 4; ++q){
        s0 = DOT2(H2(v[2*q].x),   wr[8*q+0], s0);
        s1 = DOT2(H2(v[2*q].y),   wr[8*q+1], s1);
        s2 = DOT2(H2(v[2*q].z),   wr[8*q+2], s2);
        s3 = DOT2(H2(v[2*q].w),   wr[8*q+3], s3);
        s4 = DOT2(H2(v[2*q+1].x), wr[8*q+4], s4);
        s5 = DOT2(H2(v[2*q+1].y), wr[8*q+5], s5);
        s6 = DOT2(H2(v[2*q+1].z), wr[8*q+6], s6);
        s7 = DOT2(H2(v[2*q+1].w), wr[8*q+7], s7);
    }
    return ((s0+s1)+(s2+s3)) + ((s4+s5)+(s6+s7));
}

// MERGED-CHAIN pipeline. wave0 runs BOTH recurrences interleaved (h2 lags h1
// by LAG=33): each chain's LDS broadcast round-trip hides under the other
// chain's dot issue. wave1 = u2 MFMA batches (ring1 -> u2r), wave2 = FC MFMA
// batches (ring2 -> out). Watermarks: wm[0]=h1, wm[1]=u2, wm[2]=h2, wm[3]=FC.
// All spins bounded (protocol bug -> wrong answer, never a hang).
extern "C" __global__ __launch_bounds__(256, 1)
void rnn_lastrow(const float* __restrict__ x,
                 const float* __restrict__ Wih0, const float* __restrict__ Whh0,
                 const float* __restrict__ bih0, const float* __restrict__ bhh0,
                 const float* __restrict__ Wih1, const float* __restrict__ Whh1,
                 const float* __restrict__ bih1, const float* __restrict__ bhh1,
                 const float* __restrict__ Wfc,  const float* __restrict__ bfc,
                 float* __restrict__ out)
{
    __shared__ __align__(16) u16   xl16[SEQn*16];    // x[:,4095,:] f16, rows padded to 16
    __shared__ __align__(16) float u2r[64*U2P];      // u2 ring, 64 slots
    __shared__ __align__(16) u16   ring1[64*ROW1];   // h1 history (f16)
    __shared__ __align__(16) u16   ring2[64*ROW1];   // h2 history (f16)
    __shared__ u32 wm[4];

    const int tid  = threadIdx.x;
    const int w    = tid >> 6;
    const int lane = tid & 63;
    const int g    = lane >> 4;
    const int n    = lane & 15;
    volatile u32* vwm = wm;
    const float K = 2.8853900817779268f;   // 2*log2(e)

    for (int idx = tid; idx < SEQn*16; idx += 256){
        int t = idx >> 4, j = idx & 15;
        float v = (j < INn) ? x[((long)t*BATCHn + (BATCHn-1))*INn + j] : 0.f;
        xl16[idx] = f2h(v);
    }
    for (int idx = tid; idx < 64*ROW1; idx += 256){ ring1[idx] = 0; ring2[idx] = 0; }
    if (tid < 4) wm[tid] = 0u;
    __syncthreads();

    if (w == 0){
        // ============ wave0: merged h1 + h2 chains ============
        half2_t wr0[32], wr2[32], wx[5];
        load_w16s(Whh0, lane, K, wr0);
        load_w16s(Whh1, lane, K, wr2);
        {
            const float* wxr = Wih0 + lane*INn;
#pragma unroll
            for (int q = 0; q < 4; ++q)
                wx[q] = half2_t{(_Float16)(wxr[2*q]*K), (_Float16)(wxr[2*q+1]*K)};
            wx[4] = half2_t{(_Float16)(wxr[8]*K), (_Float16)0.f};
        }
        const float b1 = (bih0[lane] + bhh0[lane]) * K;

        uint4 C1[8], C2[8];
        uint4 xa_c; u32 xb_c;
        { const u32* xr = (const u32*)(xl16); xa_c = *(const uint4*)xr; xb_c = xr[4]; }

        // ---- prologue: h1 only, p = 0..LAG-1 ----
        for (int p = 0; p < LAG; ++p){
            if ((p & 15) == 0 && p){
                asm volatile("s_waitcnt lgkmcnt(0)" ::: "memory");
                vwm[0] = (u32)p;
            }
            const uint4* hr = (const uint4*)(ring1 + ((p-1) & 63)*ROW1);
#pragma unroll
            for (int j = 0; j < 8; ++j) C1[j] = hr[j];
            float u1 = b1;
            u1 = DOT2(H2(xa_c.x), wx[0], u1);
            u1 = DOT2(H2(xa_c.y), wx[1], u1);
            u1 = DOT2(H2(xa_c.z), wx[2], u1);
            u1 = DOT2(H2(xa_c.w), wx[3], u1);
            u1 = DOT2(H2(xb_c),   wx[4], u1);
            const u32* xr = (const u32*)(xl16 + ((p+1) & (SEQn-1))*16);
            uint4 xa_n = *(const uint4*)xr; u32 xb_n = xr[4];
            float y1 = dot64r8(C1, wr0, u1);
            ring1[(p & 63)*ROW1 + lane] = f2h(tanh_pre(y1));
            xa_c = xa_n; xb_c = xb_n;
        }
        // pre-main: first u2 value + initial C2 (ring2 row 63 = zeros)
        float u2c;
        {
            int guard = 1 << 20;
            while ((vwm[1] < 16u) && --guard) __builtin_amdgcn_s_sleep(2);
            asm volatile("" ::: "memory");
            u2c = u2r[lane];                       // u2[0]
            const uint4* hr = (const uint4*)(ring2 + 63*ROW1);
#pragma unroll
            for (int j = 0; j < 8; ++j) C2[j] = hr[j];
        }
        // ---- main: i = LAG..511, h1 step p=i + h2 step c=i-LAG ----
        for (int i = LAG; i < SEQn; ++i){
            const int p = i, c = i - LAG;
            if ((i & 15) == 0){
                asm volatile("s_waitcnt lgkmcnt(0)" ::: "memory");
                vwm[0] = (u32)i;
                vwm[2] = (u32)c;
                int guard = 1 << 20;               // u2 availability through i-17
                while ((vwm[1] < (u32)(i - 16)) && --guard) __builtin_amdgcn_s_sleep(1);
                guard = 1 << 20;                   // ring2 space vs FC
                while ((vwm[3] + 48u < (u32)c) && --guard) __builtin_amdgcn_s_sleep(1);
                asm volatile("" ::: "memory");
            }
            // issue C1 <- h1[p-1] row early (latency hidden under h2 compute)
            {
                const uint4* hr = (const uint4*)(ring1 + ((p-1) & 63)*ROW1);
#pragma unroll
                for (int j = 0; j < 8; ++j) C1[j] = hr[j];
            }
            float u1 = b1;
            u1 = DOT2(H2(xa_c.x), wx[0], u1);
            u1 = DOT2(H2(xa_c.y), wx[1], u1);
            u1 = DOT2(H2(xa_c.z), wx[2], u1);
            u1 = DOT2(H2(xa_c.w), wx[3], u1);
            u1 = DOT2(H2(xb_c),   wx[4], u1);
            // h2 step (C2, u2c loaded last iter -> no stall)
            float y2 = dot64r8(C2, wr2, 0.f) + u2c;
            ring2[(c & 63)*ROW1 + lane] = f2h(tanh_pre(y2));
            // x prefetch for p+1
            const u32* xr = (const u32*)(xl16 + ((p+1) & (SEQn-1))*16);
            uint4 xa_n = *(const uint4*)xr; u32 xb_n = xr[4];
            // h1 step (C1 latency covered by u1 + h2 work above)
            float y1 = dot64r8(C1, wr0, u1);
            ring1[(p & 63)*ROW1 + lane] = f2h(tanh_pre(y1));
            // issue C2 <- h2[c] row + u2 prefetch (covered by next iter's front)
            {
                const uint4* hr = (const uint4*)(ring2 + (c & 63)*ROW1);
#pragma unroll
                for (int j = 0; j < 8; ++j) C2[j] = hr[j];
            }
            u2c = u2r[((c+1) & 63)*U2P + lane];    // max index i-16: covered by block wait
            xa_c = xa_n; xb_c = xb_n;
        }
        asm volatile("s_waitcnt lgkmcnt(0)" ::: "memory");
        vwm[0] = (u32)SEQn;
        // ---- tail: h2 only, c = SEQn-LAG..511 (direct u2 reads) ----
        for (int c = SEQn - LAG; c < SEQn; ++c){
            if ((c & 15) == 0){
                asm volatile("s_waitcnt lgkmcnt(0)" ::: "memory");
                vwm[2] = (u32)c;
                int guard = 1 << 20;
                while ((vwm[1] < (u32)(c + 16)) && --guard) __builtin_amdgcn_s_sleep(1);
                guard = 1 << 20;
                while ((vwm[3] + 48u < (u32)c) && --guard) __builtin_amdgcn_s_sleep(1);
                asm volatile("" ::: "memory");
            }
            float u2v = u2r[(c & 63)*U2P + lane];
            float y2 = dot64r8(C2, wr2, 0.f) + u2v;
            ring2[(c & 63)*ROW1 + lane] = f2h(tanh_pre(y2));
            const uint4* hr = (const uint4*)(ring2 + (c & 63)*ROW1);
#pragma unroll
            for (int j = 0; j < 8; ++j) C2[j] = hr[j];
        }
        asm volatile("s_waitcnt lgkmcnt(0)" ::: "memory");
        vwm[2] = (u32)SEQn;
    } else if (w == 1){
        // ============ wave1: u2 batches (MFMA) ============
        f16x4 wi1[4][4]; f32x4 b2f[4];
#pragma unroll
        for (int r = 0; r < 4; ++r){
            f32x4 bi1 = *(const f32x4*)&bih1[16*r + 4*g];
            f32x4 bh1 = *(const f32x4*)&bhh1[16*r + 4*g];
            b2f[r] = (bi1 + bh1) * K;
#pragma unroll
            for (int c = 0; c < 4; ++c){
                f32x4 a1 = *(const f32x4*)&Wih1[(16*r + n)*HIDn + 16*c + 4*g];
                wi1[r][c] = cvt4(a1 * K);   // A-frag: lane holds A[m=n][k=16c+4g+i]
            }
        }
        for (int b = 1; b <= 32; ++b){
            int t0 = 16*b;                 // computes u2[t0-16 .. t0)
            int guard = 1 << 20;
            while ((vwm[0] < (u32)t0) && --guard) __builtin_amdgcn_s_sleep(2);
            guard = 1 << 20;               // u2r space vs h2 consumption
            while ((vwm[2] + 64u < (u32)t0) && --guard) __builtin_amdgcn_s_sleep(2);
            asm volatile("" ::: "memory");
            f16x4 B[4];
#pragma unroll
            for (int c = 0; c < 4; ++c)    // B[k][nn] = h1[t0-16+nn][k]
                B[c] = *(const f16x4*)&ring1[((t0-16+n) & 63)*ROW1 + 16*c + 4*g];
            f32x4 D[4];
#pragma unroll
            for (int r = 0; r < 4; ++r) D[r] = b2f[r];
#pragma unroll
            for (int c = 0; c < 4; ++c)
#pragma unroll
                for (int r = 0; r < 4; ++r)
                    D[r] = MFMA16(wi1[r][c], B[c], D[r]);
            int t = (t0 - 16 + n) & 63;    // D[m][nn]: lane holds rows 16r+4g+i, col nn=n
#pragma unroll
            for (int r = 0; r < 4; ++r)
                *(f32x4*)&u2r[t*U2P + 16*r + 4*g] = D[r];
            asm volatile("s_waitcnt lgkmcnt(0)" ::: "memory");
            vwm[1] = (u32)t0;
        }
    } else if (w == 2){
        // ============ wave2: FC batches (MFMA) ============
        f16x4 wfcA[4]; f32x4 bfcf;
        {
            int mrow = (n < OUTn) ? n : (OUTn - 1);   // clamp pad rows (never stored)
#pragma unroll
            for (int c = 0; c < 4; ++c)
                wfcA[c] = cvt4(*(const f32x4*)&Wfc[mrow*HIDn + 16*c + 4*g]);  // unscaled
            int o0 = 4*g;
            bfcf.x = (o0+0 < OUTn) ? bfc[o0+0] : 0.f;
            bfcf.y = (o0+1 < OUTn) ? bfc[o0+1] : 0.f;
            bfcf.z = (o0+2 < OUTn) ? bfc[o0+2] : 0.f;
            bfcf.w = (o0+3 < OUTn) ? bfc[o0+3] : 0.f;
        }
        for (int b = 1; b <= 32; ++b){
            int f0 = 16*b;                 // FC[f0-16 .. f0)
            int guard = 1 << 20;
            while ((vwm[2] < (u32)f0) && --guard) __builtin_amdgcn_s_sleep(2);
            asm volatile("" ::: "memory");
            f16x4 B[4];
#pragma unroll
            for (int c = 0; c < 4; ++c)    // B[k][nn] = h2[f0-16+nn][k]
                B[c] = *(const f16x4*)&ring2[((f0-16+n) & 63)*ROW1 + 16*c + 4*g];
            f32x4 D = bfcf;
#pragma unroll
            for (int c = 0; c < 4; ++c)
                D = MFMA16(wfcA[c], B[c], D);
            int t = f0 - 16 + n;           // lane stores FC[t][o=4g+i]
            float* o = out + t*OUTn + 4*g;
            if (g < 2){ o[0] = D.x; o[1] = D.y; o[2] = D.z; o[3] = D.w; }
            else if (g == 2){ o[0] = D.x; o[1] = D.y; }
            asm volatile("s_waitcnt lgkmcnt(0)" ::: "memory");
            vwm[3] = (u32)f0;
        }
    }
}

extern "C" void kernel_launch(void* const* d_in, const int* in_sizes, int n_in,
                              void* d_out, int out_size, void* d_ws, size_t ws_size,
                              hipStream_t stream){
    rnn_lastrow<<<dim3(1), dim3(256), 0, stream>>>(
        (const float*)d_in[0],
        (const float*)d_in[1], (const float*)d_in[2],
        (const float*)d_in[3], (const float*)d_in[4],
        (const float*)d_in[5], (const float*)d_in[6],
        (const float*)d_in[7], (const float*)d_in[8],
        (const float*)d_in[9], (const float*)d_in[10],
        (float*)d_out);
}

// Round 8
// 246.529 us; speedup vs baseline: 1.1824x; 1.1824x over previous
//
#include <hip/hip_runtime.h>

#define SEQn   512
#define BATCHn 4096
#define INn    9
#define HIDn   64
#define OUTn   10
#define ROW1   72          // u16 elems per h-ring row (144 B)
#define U2P    72          // f32 elems per u1/u2 ring row (288 B)

typedef __attribute__((ext_vector_type(4))) float    f32x4;
typedef __attribute__((ext_vector_type(4))) _Float16 f16x4;
typedef _Float16 half2_t __attribute__((ext_vector_type(2)));
typedef unsigned short u16;
typedef unsigned int   u32;

#define MFMA16(A,B,C) __builtin_amdgcn_mfma_f32_16x16x16f16((A),(B),(C),0,0,0)

#if __has_builtin(__builtin_amdgcn_fdot2)
#define DOT2(a,b,c) __builtin_amdgcn_fdot2((a),(b),(c),false)
#else
__device__ __forceinline__ float DOT2(half2_t a, half2_t b, float c){
    return __builtin_fmaf((float)a.x,(float)b.x, __builtin_fmaf((float)a.y,(float)b.y,c));
}
#endif
#define H2(u) __builtin_bit_cast(half2_t, (u))

// tanh(y) given x = 2*log2(e)*y  (2*log2e pre-folded into weights/biases)
__device__ __forceinline__ float tanh_pre(float x){
    float e = __builtin_amdgcn_exp2f(x);
    float r = __builtin_amdgcn_rcpf(e + 1.0f);
    return __builtin_fmaf(-2.0f, r, 1.0f);
}
__device__ __forceinline__ u16 f2h(float v){ return __builtin_bit_cast(u16, (_Float16)v); }
__device__ __forceinline__ f16x4 cvt4(f32x4 a){
    f16x4 r = {(_Float16)a.x, (_Float16)a.y, (_Float16)a.z, (_Float16)a.w};
    return r;
}

// lane-owned weight row scaled by s: 64 f32 -> 32 half2 regs (for DOT2 matvec)
__device__ __forceinline__ void load_w16s(const float* __restrict__ W, int row, float s, half2_t* wr){
#pragma unroll
    for (int c = 0; c < 16; ++c){
        f32x4 v = *(const f32x4*)&W[row*HIDn + c*4];
        wr[2*c]   = half2_t{(_Float16)(v.x*s), (_Float16)(v.y*s)};
        wr[2*c+1] = half2_t{(_Float16)(v.z*s), (_Float16)(v.w*s)};
    }
}

// 64-dot, 8 accumulators x 4-deep chains; accumulator seed added by caller
__device__ __forceinline__ float dot64z(const uint4* v, const half2_t* wr){
    float s0=0.f, s1=0.f, s2=0.f, s3=0.f, s4=0.f, s5=0.f, s6=0.f, s7=0.f;
#pragma unroll
    for (int q = 0; q < 4; ++q){
        s0 = DOT2(H2(v[2*q].x),   wr[8*q+0], s0);
        s1 = DOT2(H2(v[2*q].y),   wr[8*q+1], s1);
        s2 = DOT2(H2(v[2*q].z),   wr[8*q+2], s2);
        s3 = DOT2(H2(v[2*q].w),   wr[8*q+3], s3);
        s4 = DOT2(H2(v[2*q+1].x), wr[8*q+4], s4);
        s5 = DOT2(H2(v[2*q+1].y), wr[8*q+5], s5);
        s6 = DOT2(H2(v[2*q+1].z), wr[8*q+6], s6);
        s7 = DOT2(H2(v[2*q+1].w), wr[8*q+7], s7);
    }
    return ((s0+s1)+(s2+s3)) + ((s4+s5)+(s6+s7));
}

// 4-wave pipeline. Chain waves do ONLY the recurrence (read->dot->tanh->write);
// ALL feed-forward work lives in shadow-MFMA waves:
//   wave0: h1 chain (u1 from u1r ring, prefetched 1 ahead) -> ring1
//   wave1: h2 chain (u2 from u2r ring, prefetched 1 ahead) -> ring2
//   wave2: u2 = K*(Wih1 h1 + b2) MFMA batches of 16 -> u2r
//   wave3: u1 = K*(Wih0 x + b1) MFMA batches (x straight from global) -> u1r,
//          PLUS FC MFMA batches -> out (FC drained inside u1 space-waits to
//          break the wait cycle). Watermarks: wm[0]=h1 wm[1]=u2 wm[2]=h2
//          wm[3]=FC wm[4]=u1. All spins bounded (bug -> wrong answer, no hang).
extern "C" __global__ __launch_bounds__(256, 1)
void rnn_lastrow(const float* __restrict__ x,
                 const float* __restrict__ Wih0, const float* __restrict__ Whh0,
                 const float* __restrict__ bih0, const float* __restrict__ bhh0,
                 const float* __restrict__ Wih1, const float* __restrict__ Whh1,
                 const float* __restrict__ bih1, const float* __restrict__ bhh1,
                 const float* __restrict__ Wfc,  const float* __restrict__ bfc,
                 float* __restrict__ out)
{
    __shared__ __align__(16) float u1r[64*U2P];      // u1 ring, 64 slots (f32)
    __shared__ __align__(16) float u2r[64*U2P];      // u2 ring, 64 slots (f32)
    __shared__ __align__(16) u16   ring1[64*ROW1];   // h1 history (f16)
    __shared__ __align__(16) u16   ring2[64*ROW1];   // h2 history (f16)
    __shared__ u32 wm[8];

    const int tid  = threadIdx.x;
    const int w    = tid >> 6;
    const int lane = tid & 63;
    const int g    = lane >> 4;
    const int n    = lane & 15;
    volatile u32* vwm = wm;
    const float K = 2.8853900817779268f;   // 2*log2(e)

    for (int idx = tid; idx < 64*ROW1; idx += 256){ ring1[idx] = 0; ring2[idx] = 0; }
    if (tid < 8) wm[tid] = 0u;
    __syncthreads();

    if (w == 0){
        // ============ wave0: h1 chain (recurrence only) ============
        half2_t wr0[32];
        load_w16s(Whh0, lane, K, wr0);
        uint4 C1[8];
        float u1c = 0.f;

        for (int p = 0; p < SEQn; ++p){
            if ((p & 15) == 0){
                asm volatile("s_waitcnt lgkmcnt(0)" ::: "memory");
                vwm[0] = (u32)p;
                if (p){
                    int guard = 1 << 20;   // ring1 space vs u2 consumption
                    while ((vwm[1] + 48u < (u32)p) && --guard) __builtin_amdgcn_s_sleep(1);
                }
                u32 need = (p + 32 <= SEQn) ? (u32)(p + 32) : (u32)SEQn;  // u1 thru p+16
                int guard = 1 << 20;
                while ((vwm[4] < need) && --guard) __builtin_amdgcn_s_sleep(1);
                asm volatile("" ::: "memory");
                if (p == 0) u1c = u1r[lane];
            }
            const uint4* hr = (const uint4*)(ring1 + ((p-1) & 63)*ROW1);
#pragma unroll
            for (int j = 0; j < 8; ++j) C1[j] = hr[j];
            float u1n = u1r[((p+1) & 63)*U2P + lane];   // prefetch u1[p+1]
            float y1 = dot64z(C1, wr0) + u1c;
            ring1[(p & 63)*ROW1 + lane] = f2h(tanh_pre(y1));
            u1c = u1n;
        }
        asm volatile("s_waitcnt lgkmcnt(0)" ::: "memory");
        vwm[0] = (u32)SEQn;
    } else if (w == 1){
        // ============ wave1: h2 chain (recurrence only) ============
        half2_t wr2[32];
        load_w16s(Whh1, lane, K, wr2);
        uint4 C2[8];
        float u2c = 0.f;

        for (int c = 0; c < SEQn; ++c){
            if ((c & 15) == 0){
                asm volatile("s_waitcnt lgkmcnt(0)" ::: "memory");
                vwm[2] = (u32)c;
                u32 need = (c + 32 <= SEQn) ? (u32)(c + 32) : (u32)SEQn;  // u2 thru c+16
                int guard = 1 << 20;
                while ((vwm[1] < need) && --guard) __builtin_amdgcn_s_sleep(1);
                guard = 1 << 20;           // ring2 space vs FC
                while ((vwm[3] + 48u < (u32)c) && --guard) __builtin_amdgcn_s_sleep(1);
                asm volatile("" ::: "memory");
                if (c == 0) u2c = u2r[lane];
            }
            const uint4* hr = (const uint4*)(ring2 + ((c-1) & 63)*ROW1);
#pragma unroll
            for (int j = 0; j < 8; ++j) C2[j] = hr[j];
            float u2n = u2r[((c+1) & 63)*U2P + lane];   // prefetch u2[c+1]
            float y2 = dot64z(C2, wr2) + u2c;
            ring2[(c & 63)*ROW1 + lane] = f2h(tanh_pre(y2));
            u2c = u2n;
        }
        asm volatile("s_waitcnt lgkmcnt(0)" ::: "memory");
        vwm[2] = (u32)SEQn;
    } else if (w == 2){
        // ============ wave2: u2 batches (MFMA) ============
        f16x4 wi1[4][4]; f32x4 b2f[4];
#pragma unroll
        for (int r = 0; r < 4; ++r){
            f32x4 bi1 = *(const f32x4*)&bih1[16*r + 4*g];
            f32x4 bh1 = *(const f32x4*)&bhh1[16*r + 4*g];
            b2f[r] = (bi1 + bh1) * K;
#pragma unroll
            for (int c = 0; c < 4; ++c){
                f32x4 a1 = *(const f32x4*)&Wih1[(16*r + n)*HIDn + 16*c + 4*g];
                wi1[r][c] = cvt4(a1 * K);   // A-frag: lane holds A[m=n][k=16c+4g+i]
            }
        }
        for (int b = 1; b <= 32; ++b){
            int t0 = 16*b;                 // computes u2[t0-16 .. t0)
            int guard = 1 << 20;
            while ((vwm[0] < (u32)t0) && --guard) __builtin_amdgcn_s_sleep(2);
            guard = 1 << 20;               // u2r space vs h2 consumption
            while ((vwm[2] + 64u < (u32)t0) && --guard) __builtin_amdgcn_s_sleep(2);
            asm volatile("" ::: "memory");
            f16x4 B[4];
#pragma unroll
            for (int c = 0; c < 4; ++c)    // B[k][nn] = h1[t0-16+nn][k]
                B[c] = *(const f16x4*)&ring1[((t0-16+n) & 63)*ROW1 + 16*c + 4*g];
            f32x4 D[4];
#pragma unroll
            for (int r = 0; r < 4; ++r) D[r] = b2f[r];
#pragma unroll
            for (int c = 0; c < 4; ++c)
#pragma unroll
                for (int r = 0; r < 4; ++r)
                    D[r] = MFMA16(wi1[r][c], B[c], D[r]);
            int t = (t0 - 16 + n) & 63;    // D[m][nn]: lane holds rows 16r+4g+i, col nn=n
#pragma unroll
            for (int r = 0; r < 4; ++r)
                *(f32x4*)&u2r[t*U2P + 16*r + 4*g] = D[r];
            asm volatile("s_waitcnt lgkmcnt(0)" ::: "memory");
            vwm[1] = (u32)t0;
        }
    } else {
        // ============ wave3: u1 batches (MFMA, x from global) + FC batches ============
        f16x4 wA[4]; f32x4 b1f[4];
#pragma unroll
        for (int r = 0; r < 4; ++r){
            f32x4 bi = *(const f32x4*)&bih0[16*r + 4*g];
            f32x4 bh = *(const f32x4*)&bhh0[16*r + 4*g];
            b1f[r] = (bi + bh) * K;
            // A-frag: lane (g,n) holds K*Wih0[m=16r+n][k=4g+i], k>=9 -> 0
            f16x4 e;
            const float* row = Wih0 + (16*r + n)*INn;
            int k0 = 4*g;
            e.x = (_Float16)((k0+0 < INn) ? row[k0+0]*K : 0.f);
            e.y = (_Float16)((k0+1 < INn) ? row[k0+1]*K : 0.f);
            e.z = (_Float16)((k0+2 < INn) ? row[k0+2]*K : 0.f);
            e.w = (_Float16)((k0+3 < INn) ? row[k0+3]*K : 0.f);
            wA[r] = e;
        }
        f16x4 wfcA[4]; f32x4 bfcf;
        {
            int mrow = (n < OUTn) ? n : (OUTn - 1);   // clamp pad rows (never stored)
#pragma unroll
            for (int c = 0; c < 4; ++c)
                wfcA[c] = cvt4(*(const f32x4*)&Wfc[mrow*HIDn + 16*c + 4*g]);  // unscaled
            int o0 = 4*g;
            bfcf.x = (o0+0 < OUTn) ? bfc[o0+0] : 0.f;
            bfcf.y = (o0+1 < OUTn) ? bfc[o0+1] : 0.f;
            bfcf.z = (o0+2 < OUTn) ? bfc[o0+2] : 0.f;
            bfcf.w = (o0+3 < OUTn) ? bfc[o0+3] : 0.f;
        }
        auto fcbatch = [&](int f0){        // FC[f0-16 .. f0)
            f16x4 B[4];
#pragma unroll
            for (int c = 0; c < 4; ++c)    // B[k][nn] = h2[f0-16+nn][k]
                B[c] = *(const f16x4*)&ring2[((f0-16+n) & 63)*ROW1 + 16*c + 4*g];
            f32x4 D = bfcf;
#pragma unroll
            for (int c = 0; c < 4; ++c)
                D = MFMA16(wfcA[c], B[c], D);
            int t = f0 - 16 + n;           // lane stores FC[t][o=4g+i]
            float* o = out + t*OUTn + 4*g;
            if (g < 2){ o[0] = D.x; o[1] = D.y; o[2] = D.z; o[3] = D.w; }
            else if (g == 2){ o[0] = D.x; o[1] = D.y; }
            asm volatile("s_waitcnt lgkmcnt(0)" ::: "memory");
            vwm[3] = (u32)f0;
        };

        int fc_next = 1;
        for (int b = 1; b <= 32; ++b){
            int t0 = 16*b;                 // u1[t0-16 .. t0)
            int guard = 1 << 22;           // u1r space vs h1 consumption; drain FC inside
            while ((vwm[0] + 46u < (u32)t0) && --guard){
                if (fc_next <= 32 && vwm[2] >= (u32)(16*fc_next)){
                    asm volatile("" ::: "memory");
                    fcbatch(16*fc_next); ++fc_next;
                } else __builtin_amdgcn_s_sleep(1);
            }
            asm volatile("" ::: "memory");
            // B-frag from global x: lane (g,n) loads x[t0-16+n][4g..4g+3] (pad k>=9)
            const float* xrow = x + ((long)(t0-16+n)*BATCHn + (BATCHn-1))*INn;
            f16x4 B;
            if (g < 2){
                f32x4 v = *(const f32x4*)&xrow[4*g];
                B = cvt4(v);
            } else if (g == 2){
                B = f16x4{(_Float16)xrow[8], (_Float16)0.f, (_Float16)0.f, (_Float16)0.f};
            } else {
                B = f16x4{(_Float16)0.f, (_Float16)0.f, (_Float16)0.f, (_Float16)0.f};
            }
            f32x4 D[4];
#pragma unroll
            for (int r = 0; r < 4; ++r) D[r] = MFMA16(wA[r], B, b1f[r]);
            int t = (t0 - 16 + n) & 63;    // D[m][nn]: lane holds rows 16r+4g+i, col nn=n
#pragma unroll
            for (int r = 0; r < 4; ++r)
                *(f32x4*)&u1r[t*U2P + 16*r + 4*g] = D[r];
            asm volatile("s_waitcnt lgkmcnt(0)" ::: "memory");
            vwm[4] = (u32)t0;
            while (fc_next <= 32 && vwm[2] >= (u32)(16*fc_next)){
                asm volatile("" ::: "memory");
                fcbatch(16*fc_next); ++fc_next;
            }
        }
        while (fc_next <= 32){
            int guard = 1 << 20;
            while ((vwm[2] < (u32)(16*fc_next)) && --guard) __builtin_amdgcn_s_sleep(2);
            asm volatile("" ::: "memory");
            fcbatch(16*fc_next); ++fc_next;
        }
    }
}

extern "C" void kernel_launch(void* const* d_in, const int* in_sizes, int n_in,
                              void* d_out, int out_size, void* d_ws, size_t ws_size,
                              hipStream_t stream){
    rnn_lastrow<<<dim3(1), dim3(256), 0, stream>>>(
        (const float*)d_in[0],
        (const float*)d_in[1], (const float*)d_in[2],
        (const float*)d_in[3], (const float*)d_in[4],
        (const float*)d_in[5], (const float*)d_in[6],
        (const float*)d_in[7], (const float*)d_in[8],
        (const float*)d_in[9], (const float*)d_in[10],
        (float*)d_out);
}